// Round 15
// baseline (226.378 us; speedup 1.0000x reference)
//
#include <hip/hip_runtime.h>

// SNN forward, 2-kernel compute core:
//   [GEMM1 + scan1 + partial-GEMM2 fused] -> [sum partials + scan2]
// g1s1: 128x128 tiles, LDS-dbuf K-loop (R10 optimum). After the in-LDS scan,
// each block MFMAs its spike tile (128t x 128h) against its W2 slice
// (fragment-order W2f, L2-resident) and writes partial y2 per ht.
// s1b (64MB write + 65MB read) never materializes; gemm2 kernel deleted.
// f16 split-2: W = hi + lo, residual ~2^-24 => fp32-grade MFMA results.
// Lessons: compile-time ring/dbuf indices (R9); LDS-dbuf beats register-dbuf
// (R11/R12 VGPR cliff); partial-sum reorder is spike-safe (R8 split-K).

#define NN 64
#define II 256
#define HH 1024
#define OO 18
#define TT 500

#define D_SR 0.9048374180359595f   // exp(-1/10)
#define C_SR 0.27182818284590454f  // e/10
#define D_RF 0.36787944117144233f  // exp(-1)
#define C_RF 2.718281828459045f    // e
#define THETA 10.0f
#define REFS (-20.0f)

typedef _Float16 f16;
typedef _Float16 f16x8 __attribute__((ext_vector_type(8)));
typedef float f32x4 __attribute__((ext_vector_type(4)));

__device__ __forceinline__ void gl2lds16(const void* g, void* l) {
    __builtin_amdgcn_global_load_lds(
        (const __attribute__((address_space(1))) void*)g,
        (__attribute__((address_space(3))) void*)l, 16, 0, 0);
}

// ---------------- prep: X [N][I][T] f32 -> Xb [N*T][I] f16 (transpose) -----
__launch_bounds__(256)
__global__ void prep_x(const float* __restrict__ X, f16* __restrict__ Xb) {
    __shared__ float tile[64][65];
    const int n = blockIdx.z, i0 = blockIdx.y * 64, t0 = blockIdx.x * 64;
    const int tx = threadIdx.x & 63, q = threadIdx.x >> 6;
    const float* Xn = X + (size_t)n * II * TT;
#pragma unroll 4
    for (int j = 0; j < 16; ++j) {
        int il = j * 4 + q;
        int t = t0 + tx;
        tile[il][tx] = (t < TT) ? Xn[(size_t)(i0 + il) * TT + t] : 0.f;
    }
    __syncthreads();
#pragma unroll 4
    for (int j = 0; j < 16; ++j) {
        int tl = j * 4 + q;
        int t = t0 + tl;
        if (t < TT)
            Xb[((size_t)n * TT + t) * II + i0 + tx] = (f16)tile[tx][tl];
    }
}

// ---------------- prep: W1 -> f16 hi/lo [H][I] ------------------------------
__launch_bounds__(256)
__global__ void prep_w1(const float* __restrict__ W1, f16* __restrict__ Wh,
                        f16* __restrict__ Wl) {
    int idx = blockIdx.x * 256 + threadIdx.x;
    float w = W1[idx];
    f16 h = (f16)w;
    f16 l = (f16)(w - (float)h);
    Wh[idx] = h;
    Wl[idx] = l;
}

// ---------------- prep: W2 -> B-fragment-order f16 hi/lo per ht slice -------
// Layout: Wf[ht 8][(j*4+kk) 8][fr*32 + kq*8 + e]  (512 f16 per frag-tile)
// Fragment (j,kk): lane(fr,kq) holds B[k=kk*32+kq*8+e][o=j*16+fr]
__launch_bounds__(256)
__global__ void prep_w2f(const float* __restrict__ W2, f16* __restrict__ Wfh,
                         f16* __restrict__ Wfl) {
    int idx = blockIdx.x * 256 + threadIdx.x;  // < 4096
    int kq = idx & 3, fr = (idx >> 2) & 15, kk = (idx >> 6) & 3;
    int j = (idx >> 8) & 1, ht = idx >> 9;
    int o = j * 16 + fr;
    int h0 = ht * 128 + kk * 32 + kq * 8;
    f16x8 h, l;
#pragma unroll
    for (int e = 0; e < 8; ++e) {
        float w = (o < OO) ? W2[(size_t)o * HH + h0 + e] : 0.f;
        f16 hh = (f16)w;
        h[e] = hh;
        l[e] = (f16)(w - (float)hh);
    }
    size_t dst = ((size_t)ht * 8 + j * 4 + kk) * 512 + fr * 32 + kq * 8;
    *(f16x8*)(Wfh + dst) = h;
    *(f16x8*)(Wfl + dst) = l;
}

// ---------------- FUSED layer 1 + partial layer 2 ---------------------------
// grid (8, 64), 256 thr. Per block: 4 t-chunks of 128.
// Chunk: [LDS-dbuf K-loop, 1 barrier/iter] -> epilogue->yb -> barrier ->
// scan (tid<128, spikes -> yb) -> barrier -> partial-GEMM2 (all waves:
// spike frags from yb f32->f16, W2 frags from global L2, 32 MFMA,
// partial y2 -> global) -> barrier.
__launch_bounds__(256)
__global__ void gemm1_scan1(const f16* __restrict__ Xb, const f16* __restrict__ Wh,
                            const f16* __restrict__ Wl, const f16* __restrict__ W2fh,
                            const f16* __restrict__ W2fl, float* __restrict__ Y2p) {
    __shared__ __align__(16) char smem[128 * 132 * 4];  // 67,584 B
    float* yb = (float*)smem;

    const int tid = threadIdx.x;
    const int wave = tid >> 6, lane = tid & 63;

    // XCD swizzle: the 8 h-tiles of one n share an XCD
    const int f = blockIdx.y * 8 + blockIdx.x;
    const int x = f & 7, g = f >> 3;
    const int n = x * 8 + (g & 7);
    const int ht = g >> 3;
    const int h0g = ht * 128;

    const int rbl = wave * 32 + (lane >> 2);
    const int koff = (lane & 3) * 8;
    const f16* gBh0 = Wh + (size_t)(h0g + rbl) * II + koff;
    const f16* gBl0 = Wl + (size_t)(h0g + rbl) * II + koff;

    const int wm = wave & 1, wn = wave >> 1;
    const int fr = lane & 15, kq = lane >> 4;

    // W2 fragment pointers (fixed): frag (j,kk) at + (j*4+kk)*512
    const f16* bfh = W2fh + (size_t)ht * 4096 + fr * 32 + kq * 8;
    const f16* bfl = W2fl + (size_t)ht * 4096 + fr * 32 + kq * 8;

    float p1 = 0.f, a1 = 0.f, p2 = 0.f, a2 = 0.f;  // scan state (tid<128)

    for (int c = 0; c < 4; ++c) {
        const int t0 = c * 128;
        const int TCe = (TT - t0 < 128) ? (TT - t0) : 128;

        int r0 = rbl;      if (r0 > TCe - 1) r0 = TCe - 1;
        int r1 = rbl + 16; if (r1 > TCe - 1) r1 = TCe - 1;
        const f16* gA0 = Xb + ((size_t)n * TT + t0 + r0) * II + koff;
        const f16* gA1 = Xb + ((size_t)n * TT + t0 + r1) * II + koff;

        auto stage = [&](int kk2, int b) {
            f16* As_b = (f16*)(smem + b * 24576);
            f16* Bh_b = As_b + 4096;
            f16* Bl_b = As_b + 8192;
            const int ko = kk2 * 32;
            gl2lds16(gA0 + ko, As_b + wave * 1024);
            gl2lds16(gA1 + ko, As_b + wave * 1024 + 512);
            gl2lds16(gBh0 + ko, Bh_b + wave * 1024);
            gl2lds16(gBh0 + 16 * II + ko, Bh_b + wave * 1024 + 512);
            gl2lds16(gBl0 + ko, Bl_b + wave * 1024);
            gl2lds16(gBl0 + 16 * II + ko, Bl_b + wave * 1024 + 512);
        };

        stage(0, 0);  // previous chunk's final barrier protects yb base

        f32x4 acc[4][4] = {};
        for (int kk = 0; kk < 8; ++kk) {
            __syncthreads();                 // buf[kk&1] DMA drained here
            if (kk < 7) stage(kk + 1, (kk + 1) & 1);

            const f16* As_b = (const f16*)(smem + (kk & 1) * 24576);
            const f16* Bh_b = As_b + 4096;
            const f16* Bl_b = As_b + 8192;

            f16x8 av[4], bhv[4], blv[4];
#pragma unroll
            for (int i = 0; i < 4; ++i) {
                av[i]  = *(const f16x8*)(As_b + (wm * 64 + i * 16 + fr) * 32 + kq * 8);
                bhv[i] = *(const f16x8*)(Bh_b + (wn * 64 + i * 16 + fr) * 32 + kq * 8);
                blv[i] = *(const f16x8*)(Bl_b + (wn * 64 + i * 16 + fr) * 32 + kq * 8);
            }
#pragma unroll
            for (int i = 0; i < 4; ++i)
#pragma unroll
                for (int j = 0; j < 4; ++j) {
                    acc[i][j] = __builtin_amdgcn_mfma_f32_16x16x32_f16(av[i], bhv[j], acc[i][j], 0, 0, 0);
                    acc[i][j] = __builtin_amdgcn_mfma_f32_16x16x32_f16(av[i], blv[j], acc[i][j], 0, 0, 0);
                }
        }
        __syncthreads();  // all frag reads done before epilogue overwrites staging

        // epilogue: acc -> yb (t-major, stride 132)
#pragma unroll
        for (int i = 0; i < 4; ++i)
#pragma unroll
            for (int j = 0; j < 4; ++j) {
                int tr = wm * 64 + i * 16 + kq * 4;
                int hc = wn * 64 + j * 16 + fr;
#pragma unroll
                for (int r = 0; r < 4; ++r)
                    yb[(tr + r) * 132 + hc] = acc[i][j][r];
            }
        __syncthreads();

        // sequential scan; 8-deep LDS prefetch ring; spikes back into yb
        if (tid < 128) {
            float rb_[8];
#pragma unroll
            for (int j = 0; j < 8; ++j) rb_[j] = yb[j * 132 + tid];
            int t = 0;
            for (; t + 8 <= TCe; t += 8) {
#pragma unroll
                for (int j = 0; j < 8; ++j) {
                    float xv = rb_[j];
                    int tn = t + j + 8;
                    rb_[j] = (tn < TCe) ? yb[tn * 132 + tid] : 0.f;
                    a1 = D_SR * (a1 + p1);
                    p1 = D_SR * p1 + xv;
                    float ut = C_SR * a1;
                    a2 = D_RF * (a2 + p2);
                    float u = ut + C_RF * a2;
                    float s = (u >= THETA) ? 1.0f : 0.0f;
                    p2 = D_RF * p2 + REFS * s;
                    yb[(t + j) * 132 + tid] = s;
                }
            }
            int rem = TCe - t;
#pragma unroll
            for (int j = 0; j < 8; ++j) {
                if (j < rem) {
                    float xv = rb_[j];
                    a1 = D_SR * (a1 + p1);
                    p1 = D_SR * p1 + xv;
                    float ut = C_SR * a1;
                    a2 = D_RF * (a2 + p2);
                    float u = ut + C_RF * a2;
                    float s = (u >= THETA) ? 1.0f : 0.0f;
                    p2 = D_RF * p2 + REFS * s;
                    yb[(t + j) * 132 + tid] = s;
                }
            }
        }
        __syncthreads();  // spikes visible to all waves

        // partial GEMM2: spikes(128x128) x W2slice^T -> y2p[ht] (t0 rows)
        {
            f16x8 bh2[2][4], bl2[2][4];
#pragma unroll
            for (int j = 0; j < 2; ++j)
#pragma unroll
                for (int kk = 0; kk < 4; ++kk) {
                    bh2[j][kk] = *(const f16x8*)(bfh + (j * 4 + kk) * 512);
                    bl2[j][kk] = *(const f16x8*)(bfl + (j * 4 + kk) * 512);
                }
#pragma unroll
            for (int i = 0; i < 2; ++i) {
                f16x8 sf[4];
#pragma unroll
                for (int kk = 0; kk < 4; ++kk) {
                    const float* sp = yb + (wave * 32 + i * 16 + fr) * 132 + kk * 32 + kq * 8;
                    float4 v0 = *(const float4*)(sp);
                    float4 v1 = *(const float4*)(sp + 4);
                    f16x8 tv;
                    tv[0] = (f16)v0.x; tv[1] = (f16)v0.y; tv[2] = (f16)v0.z; tv[3] = (f16)v0.w;
                    tv[4] = (f16)v1.x; tv[5] = (f16)v1.y; tv[6] = (f16)v1.z; tv[7] = (f16)v1.w;
                    sf[kk] = tv;
                }
                f32x4 acc2[2] = {};
#pragma unroll
                for (int kk = 0; kk < 4; ++kk)
#pragma unroll
                    for (int j = 0; j < 2; ++j) {
                        acc2[j] = __builtin_amdgcn_mfma_f32_16x16x32_f16(sf[kk], bh2[j][kk], acc2[j], 0, 0, 0);
                        acc2[j] = __builtin_amdgcn_mfma_f32_16x16x32_f16(sf[kk], bl2[j][kk], acc2[j], 0, 0, 0);
                    }
                const int rbase = wave * 32 + i * 16 + kq * 4;
#pragma unroll
                for (int j = 0; j < 2; ++j) {
#pragma unroll
                    for (int r = 0; r < 4; ++r) {
                        int t = t0 + rbase + r;
                        if (t < TT)
                            Y2p[(((size_t)ht * NN + n) * TT + t) * 32 + j * 16 + fr] = acc2[j][r];
                    }
                }
            }
        }
        __syncthreads();  // yb reads done; next chunk's staging may overwrite
    }
}

// ---------------- scan2: sum 8 partials -> LDS -> static-ring scan ----------
// grid 64 (n), 256 thr. Coalesced float4 loads of 8 ht streams, summed
// ht 0..7 left-to-right, staged in LDS; 32 lanes scan with unrolled ring.
__launch_bounds__(256)
__global__ void scan2_k(const float* __restrict__ Y2p, float* __restrict__ Out) {
    __shared__ float yc[TT * 32];    // 64,000 B
    __shared__ float sb[OO * TT];    // 36,000 B
    const int n = blockIdx.x, tid = threadIdx.x;

    const float4* s0 = (const float4*)(Y2p + (size_t)n * TT * 32);
    const size_t hstr = (size_t)NN * TT * 32 / 4;  // float4 stride per ht
    float4* dst = (float4*)yc;
    for (int i = tid; i < TT * 8; i += 256) {
        float4 a = s0[i];
#pragma unroll
        for (int ht = 1; ht < 8; ++ht) {
            float4 b = s0[i + (size_t)ht * hstr];
            a.x += b.x; a.y += b.y; a.z += b.z; a.w += b.w;
        }
        dst[i] = a;
    }
    __syncthreads();

    if (tid < 32) {
        float p1 = 0.f, a1 = 0.f, p2 = 0.f, a2 = 0.f;
        float rb_[8];
#pragma unroll
        for (int j = 0; j < 8; ++j) rb_[j] = yc[j * 32 + tid];
        int t = 0;
        for (; t + 8 <= TT; t += 8) {
#pragma unroll
            for (int j = 0; j < 8; ++j) {
                float xv = rb_[j];
                int tn = t + j + 8;
                rb_[j] = (tn < TT) ? yc[tn * 32 + tid] : 0.f;
                a1 = D_SR * (a1 + p1);
                p1 = D_SR * p1 + xv;
                float ut = C_SR * a1;
                a2 = D_RF * (a2 + p2);
                float u = ut + C_RF * a2;
                float s = (u >= THETA) ? 1.0f : 0.0f;
                p2 = D_RF * p2 + REFS * s;
                if (tid < OO) sb[tid * TT + t + j] = s;
            }
        }
#pragma unroll
        for (int j = 0; j < 8; ++j) {
            if (t + j < TT) {
                float xv = rb_[j];
                a1 = D_SR * (a1 + p1);
                p1 = D_SR * p1 + xv;
                float ut = C_SR * a1;
                a2 = D_RF * (a2 + p2);
                float u = ut + C_RF * a2;
                float s = (u >= THETA) ? 1.0f : 0.0f;
                p2 = D_RF * p2 + REFS * s;
                if (tid < OO) sb[tid * TT + t + j] = s;
            }
        }
    }
    __syncthreads();

    float* on = Out + (size_t)n * OO * TT;
    for (int e = tid; e < OO * TT; e += 256) on[e] = sb[e];
}

extern "C" void kernel_launch(void* const* d_in, const int* in_sizes, int n_in,
                              void* d_out, int out_size, void* d_ws, size_t ws_size,
                              hipStream_t stream) {
    const float* X  = (const float*)d_in[0];
    const float* W1 = (const float*)d_in[1];
    const float* W2 = (const float*)d_in[2];
    float* out = (float*)d_out;

    const size_t s_y2p = (size_t)8 * NN * TT * 32 * 4;  // 32,768,000
    const size_t s_Xb  = (size_t)NN * TT * II * 2;      // 16,384,000
    const size_t s_W   = (size_t)HH * II * 2;           //    524,288 (x2)
    const size_t s_W2f = (size_t)8 * 4096 * 2;          //     65,536 (x2)
    // total ~50.3 MB

    char* w = (char*)d_ws;
    float* y2p  = (float*)w;  w += s_y2p;
    f16*   Xb   = (f16*)w;    w += s_Xb;
    f16*   W1h  = (f16*)w;    w += s_W;
    f16*   W1l  = (f16*)w;    w += s_W;
    f16*   W2fh = (f16*)w;    w += s_W2f;
    f16*   W2fl = (f16*)w;    w += s_W2f;

    prep_x<<<dim3(8, 4, NN), 256, 0, stream>>>(X, Xb);
    prep_w1<<<(HH * II) / 256, 256, 0, stream>>>(W1, W1h, W1l);
    prep_w2f<<<16, 256, 0, stream>>>(W2, W2fh, W2fl);

    gemm1_scan1<<<dim3(8, NN), 256, 0, stream>>>(Xb, W1h, W1l, W2fh, W2fl, y2p);

    scan2_k<<<NN, 256, 0, stream>>>(y2p, out);
}

// Round 16
// 191.112 us; speedup vs baseline: 1.1845x; 1.1845x over previous
//
#include <hip/hip_runtime.h>

// SNN forward (best-known consolidated): [merged preps] ->
// [GEMM1+scan1 fused, 128x128, LDS-dbuf K-loop] -> GEMM2 (64-row, 500 blk)
// -> scan2 (single-phase LDS, static ring).
// f16 split-2: W = hi + lo (both f16), residual ~2^-24 => fp32-grade MFMA.
// Lessons: compile-time ring/dbuf indices (R9); LDS-staged dbuf optimum for
// g1s1 (R10; register-dbuf = VGPR cliff R11/R12; deeper pipes defeated by
// barrier vmcnt(0) drain); partial-GEMM2 fusion serializes at a net loss (R14).

#define NN 64
#define II 256
#define HH 1024
#define OO 18
#define TT 500

#define D_SR 0.9048374180359595f   // exp(-1/10)
#define C_SR 0.27182818284590454f  // e/10
#define D_RF 0.36787944117144233f  // exp(-1)
#define C_RF 2.718281828459045f    // e
#define THETA 10.0f
#define REFS (-20.0f)

typedef _Float16 f16;
typedef _Float16 f16x8 __attribute__((ext_vector_type(8)));
typedef float f32x4 __attribute__((ext_vector_type(4)));

__device__ __forceinline__ void gl2lds16(const void* g, void* l) {
    __builtin_amdgcn_global_load_lds(
        (const __attribute__((address_space(1))) void*)g,
        (__attribute__((address_space(3))) void*)l, 16, 0, 0);
}

// ---------------- merged prep: X transpose + W1 hi/lo + W2 hi/lo ------------
// grid 3200: [0,2048) prep_x tiles, [2048,3072) W1, [3072,3200) W2.
__launch_bounds__(256)
__global__ void prep_all(const float* __restrict__ X, const float* __restrict__ W1,
                         const float* __restrict__ W2, f16* __restrict__ Xb,
                         f16* __restrict__ W1h, f16* __restrict__ W1l,
                         f16* __restrict__ W2h, f16* __restrict__ W2l) {
    __shared__ float tile[64][65];
    const int b = blockIdx.x;
    const int tid = threadIdx.x;

    if (b < 2048) {
        // prep_x: X [N][I][T] f32 -> Xb [N*T][I] f16 (transpose)
        const int t0 = (b & 7) * 64, i0 = ((b >> 3) & 3) * 64, n = b >> 5;
        const int tx = tid & 63, q = tid >> 6;
        const float* Xn = X + (size_t)n * II * TT;
#pragma unroll 4
        for (int j = 0; j < 16; ++j) {
            int il = j * 4 + q;
            int t = t0 + tx;
            tile[il][tx] = (t < TT) ? Xn[(size_t)(i0 + il) * TT + t] : 0.f;
        }
        __syncthreads();
#pragma unroll 4
        for (int j = 0; j < 16; ++j) {
            int tl = j * 4 + q;
            int t = t0 + tl;
            if (t < TT)
                Xb[((size_t)n * TT + t) * II + i0 + tx] = (f16)tile[tx][tl];
        }
    } else if (b < 3072) {
        // prep_w1: W1 -> f16 hi/lo [H][I]
        int idx = (b - 2048) * 256 + tid;
        float w = W1[idx];
        f16 h = (f16)w;
        f16 l = (f16)(w - (float)h);
        W1h[idx] = h;
        W1l[idx] = l;
    } else {
        // prep_w2: W2 -> f16 hi/lo [32 padded][H]
        int idx = (b - 3072) * 256 + tid;
        int o = idx >> 10;
        float w = (o < OO) ? W2[idx] : 0.f;
        f16 h = (f16)w;
        f16 l = (f16)(w - (float)h);
        W2h[idx] = h;
        W2l[idx] = l;
    }
}

// ---------------- FUSED layer 1: 128x128 tile, dbuf K-loop (R10 optimum) ----
__launch_bounds__(256)
__global__ void gemm1_scan1(const f16* __restrict__ Xb, const f16* __restrict__ Wh,
                            const f16* __restrict__ Wl, f16* __restrict__ S1) {
    __shared__ __align__(16) char smem[128 * 132 * 4];  // 67,584 B
    float* yb = (float*)smem;

    const int tid = threadIdx.x;
    const int wave = tid >> 6, lane = tid & 63;

    // XCD swizzle: the 8 h-tiles of one n share an XCD
    const int f = blockIdx.y * 8 + blockIdx.x;
    const int x = f & 7, g = f >> 3;
    const int n = x * 8 + (g & 7);
    const int ht = g >> 3;
    const int h0g = ht * 128;

    const int rbl = wave * 32 + (lane >> 2);
    const int koff = (lane & 3) * 8;
    const f16* gBh0 = Wh + (size_t)(h0g + rbl) * II + koff;
    const f16* gBl0 = Wl + (size_t)(h0g + rbl) * II + koff;

    const int wm = wave & 1, wn = wave >> 1;
    const int fr = lane & 15, kq = lane >> 4;

    float p1 = 0.f, a1 = 0.f, p2 = 0.f, a2 = 0.f;  // scan state (tid<128)

    for (int c = 0; c < 4; ++c) {
        const int t0 = c * 128;
        const int TCe = (TT - t0 < 128) ? (TT - t0) : 128;

        int r0 = rbl;      if (r0 > TCe - 1) r0 = TCe - 1;
        int r1 = rbl + 16; if (r1 > TCe - 1) r1 = TCe - 1;
        const f16* gA0 = Xb + ((size_t)n * TT + t0 + r0) * II + koff;
        const f16* gA1 = Xb + ((size_t)n * TT + t0 + r1) * II + koff;

        auto stage = [&](int kk2, int b) {
            f16* As_b = (f16*)(smem + b * 24576);
            f16* Bh_b = As_b + 4096;
            f16* Bl_b = As_b + 8192;
            const int ko = kk2 * 32;
            gl2lds16(gA0 + ko, As_b + wave * 1024);
            gl2lds16(gA1 + ko, As_b + wave * 1024 + 512);
            gl2lds16(gBh0 + ko, Bh_b + wave * 1024);
            gl2lds16(gBh0 + 16 * II + ko, Bh_b + wave * 1024 + 512);
            gl2lds16(gBl0 + ko, Bl_b + wave * 1024);
            gl2lds16(gBl0 + 16 * II + ko, Bl_b + wave * 1024 + 512);
        };

        stage(0, 0);  // previous chunk's post-scan barrier protects yb base

        f32x4 acc[4][4] = {};
        for (int kk = 0; kk < 8; ++kk) {
            __syncthreads();                 // buf[kk&1] DMA drained here
            if (kk < 7) stage(kk + 1, (kk + 1) & 1);

            const f16* As_b = (const f16*)(smem + (kk & 1) * 24576);
            const f16* Bh_b = As_b + 4096;
            const f16* Bl_b = As_b + 8192;

            f16x8 av[4], bhv[4], blv[4];
#pragma unroll
            for (int i = 0; i < 4; ++i) {
                av[i]  = *(const f16x8*)(As_b + (wm * 64 + i * 16 + fr) * 32 + kq * 8);
                bhv[i] = *(const f16x8*)(Bh_b + (wn * 64 + i * 16 + fr) * 32 + kq * 8);
                blv[i] = *(const f16x8*)(Bl_b + (wn * 64 + i * 16 + fr) * 32 + kq * 8);
            }
#pragma unroll
            for (int i = 0; i < 4; ++i)
#pragma unroll
                for (int j = 0; j < 4; ++j) {
                    acc[i][j] = __builtin_amdgcn_mfma_f32_16x16x32_f16(av[i], bhv[j], acc[i][j], 0, 0, 0);
                    acc[i][j] = __builtin_amdgcn_mfma_f32_16x16x32_f16(av[i], blv[j], acc[i][j], 0, 0, 0);
                }
        }
        __syncthreads();  // all frag reads done before epilogue overwrites staging

        // epilogue: acc -> yb (t-major, stride 132)
#pragma unroll
        for (int i = 0; i < 4; ++i)
#pragma unroll
            for (int j = 0; j < 4; ++j) {
                int tr = wm * 64 + i * 16 + kq * 4;
                int hc = wn * 64 + j * 16 + fr;
#pragma unroll
                for (int r = 0; r < 4; ++r)
                    yb[(tr + r) * 132 + hc] = acc[i][j][r];
            }
        __syncthreads();

        // sequential scan; 8-deep LDS prefetch ring; spikes -> global directly
        if (tid < 128) {
            f16* sq = S1 + ((size_t)n * TT + t0) * HH + h0g + tid;
            float rb_[8];
#pragma unroll
            for (int j = 0; j < 8; ++j) rb_[j] = yb[j * 132 + tid];
            int t = 0;
            for (; t + 8 <= TCe; t += 8) {
#pragma unroll
                for (int j = 0; j < 8; ++j) {
                    float xv = rb_[j];
                    int tn = t + j + 8;
                    rb_[j] = (tn < TCe) ? yb[tn * 132 + tid] : 0.f;
                    a1 = D_SR * (a1 + p1);
                    p1 = D_SR * p1 + xv;
                    float ut = C_SR * a1;
                    a2 = D_RF * (a2 + p2);
                    float u = ut + C_RF * a2;
                    float s = (u >= THETA) ? 1.0f : 0.0f;
                    p2 = D_RF * p2 + REFS * s;
                    sq[(size_t)(t + j) * HH] = (f16)s;
                }
            }
            int rem = TCe - t;
#pragma unroll
            for (int j = 0; j < 8; ++j) {
                if (j < rem) {
                    float xv = rb_[j];
                    a1 = D_SR * (a1 + p1);
                    p1 = D_SR * p1 + xv;
                    float ut = C_SR * a1;
                    a2 = D_RF * (a2 + p2);
                    float u = ut + C_RF * a2;
                    float s = (u >= THETA) ? 1.0f : 0.0f;
                    p2 = D_RF * p2 + REFS * s;
                    sq[(size_t)(t + j) * HH] = (f16)s;
                }
            }
        }
        __syncthreads();  // yb reads done; next chunk's staging may overwrite
    }
}

// ---------------- GEMM2 (MFMA, split-f16, dbuf, 64-row tiles) ---------------
// grid 500 (2 blocks/CU); 256 thr; tile 64 m x 32 o; K=1024, BK=32.
__launch_bounds__(256)
__global__ void gemm2_mfma(const f16* __restrict__ S1, const f16* __restrict__ W2h,
                           const f16* __restrict__ W2l, float* __restrict__ Y2) {
    __shared__ __align__(16) f16 As[2][64 * 32];  // 2 x 4 KB
    __shared__ __align__(16) f16 Bh[2][32 * 32];  // 2 x 2 KB
    __shared__ __align__(16) f16 Bl[2][32 * 32];  // 2 x 2 KB

    const int tid = threadIdx.x;
    const int wave = tid >> 6, lane = tid & 63;
    const int m0 = blockIdx.x * 64;
    const int fr = lane & 15, kq = lane >> 4;

    const f16* gA = S1 + (size_t)(m0 + wave * 16 + (lane >> 2)) * HH + (lane & 3) * 8;
    const f16* gB = (wave < 2 ? W2h : W2l) + (size_t)((wave & 1) * 16 + (lane >> 2)) * HH + (lane & 3) * 8;

    auto stage = [&](int kk2, int b) {
        const int ko = kk2 * 32;
        gl2lds16(gA + ko, &As[b][wave * 512]);
        gl2lds16(gB + ko, (wave < 2 ? &Bh[b][0] : &Bl[b][0]) + (wave & 1) * 512);
    };

    stage(0, 0);

    f32x4 acc[2] = {};
    for (int kk = 0; kk < HH / 32; ++kk) {
        __syncthreads();
        if (kk < HH / 32 - 1) stage(kk + 1, (kk + 1) & 1);
        const int b = kk & 1;

        f16x8 a, bh[2], bl[2];
        a = *(const f16x8*)(&As[b][(wave * 16 + fr) * 32 + kq * 8]);
#pragma unroll
        for (int j = 0; j < 2; ++j) {
            bh[j] = *(const f16x8*)(&Bh[b][(j * 16 + fr) * 32 + kq * 8]);
            bl[j] = *(const f16x8*)(&Bl[b][(j * 16 + fr) * 32 + kq * 8]);
        }
#pragma unroll
        for (int j = 0; j < 2; ++j) {
            acc[j] = __builtin_amdgcn_mfma_f32_16x16x32_f16(a, bh[j], acc[j], 0, 0, 0);
            acc[j] = __builtin_amdgcn_mfma_f32_16x16x32_f16(a, bl[j], acc[j], 0, 0, 0);
        }
    }

#pragma unroll
    for (int j = 0; j < 2; ++j) {
        int rbase = m0 + wave * 16 + kq * 4;
        int cc = j * 16 + fr;
        float* p = Y2 + (size_t)rbase * 32 + cc;
#pragma unroll
        for (int r = 0; r < 4; ++r)
            p[(size_t)r * 32] = acc[j][r];
    }
}

// ---------------- scan2: single-phase LDS, static-index ring ----------------
__launch_bounds__(256)
__global__ void scan2_k(const float* __restrict__ Y2, float* __restrict__ Out) {
    __shared__ float yc[TT * 32];    // 64,000 B
    __shared__ float sb[OO * TT];    // 36,000 B
    const int n = blockIdx.x, tid = threadIdx.x;

    const float4* src = (const float4*)(Y2 + (size_t)n * TT * 32);
    float4* dst = (float4*)yc;
    for (int i = tid; i < TT * 8; i += 256) dst[i] = src[i];
    __syncthreads();

    if (tid < 32) {
        float p1 = 0.f, a1 = 0.f, p2 = 0.f, a2 = 0.f;
        float rb_[8];
#pragma unroll
        for (int j = 0; j < 8; ++j) rb_[j] = yc[j * 32 + tid];
        int t = 0;
        for (; t + 8 <= TT; t += 8) {
#pragma unroll
            for (int j = 0; j < 8; ++j) {
                float xv = rb_[j];
                int tn = t + j + 8;
                rb_[j] = (tn < TT) ? yc[tn * 32 + tid] : 0.f;
                a1 = D_SR * (a1 + p1);
                p1 = D_SR * p1 + xv;
                float ut = C_SR * a1;
                a2 = D_RF * (a2 + p2);
                float u = ut + C_RF * a2;
                float s = (u >= THETA) ? 1.0f : 0.0f;
                p2 = D_RF * p2 + REFS * s;
                if (tid < OO) sb[tid * TT + t + j] = s;
            }
        }
#pragma unroll
        for (int j = 0; j < 8; ++j) {
            if (t + j < TT) {
                float xv = rb_[j];
                a1 = D_SR * (a1 + p1);
                p1 = D_SR * p1 + xv;
                float ut = C_SR * a1;
                a2 = D_RF * (a2 + p2);
                float u = ut + C_RF * a2;
                float s = (u >= THETA) ? 1.0f : 0.0f;
                p2 = D_RF * p2 + REFS * s;
                if (tid < OO) sb[tid * TT + t + j] = s;
            }
        }
    }
    __syncthreads();

    float* on = Out + (size_t)n * OO * TT;
    for (int e = tid; e < OO * TT; e += 256) on[e] = sb[e];
}

extern "C" void kernel_launch(void* const* d_in, const int* in_sizes, int n_in,
                              void* d_out, int out_size, void* d_ws, size_t ws_size,
                              hipStream_t stream) {
    const float* X  = (const float*)d_in[0];
    const float* W1 = (const float*)d_in[1];
    const float* W2 = (const float*)d_in[2];
    float* out = (float*)d_out;

    const size_t s_s1 = (size_t)NN * TT * HH * 2;   // 65,536,000
    const size_t s_Xb = (size_t)NN * TT * II * 2;   // 16,384,000
    const size_t s_W  = (size_t)HH * II * 2;        //    524,288 (x2)
    const size_t s_W2 = (size_t)32 * HH * 2;        //     65,536 (x2)
    // + y2 4,096,000 => ~87 MB total

    char* w = (char*)d_ws;
    f16*   s1b = (f16*)w;  w += s_s1;
    f16*   Xb  = (f16*)w;  w += s_Xb;
    f16*   W1h = (f16*)w;  w += s_W;
    f16*   W1l = (f16*)w;  w += s_W;
    f16*   W2h = (f16*)w;  w += s_W2;
    f16*   W2l = (f16*)w;  w += s_W2;
    float* y2  = (float*)w;

    prep_all<<<3200, 256, 0, stream>>>(X, W1, W2, Xb, W1h, W1l, W2h, W2l);

    gemm1_scan1<<<dim3(8, NN), 256, 0, stream>>>(Xb, W1h, W1l, s1b);

    gemm2_mfma<<<(NN * TT) / 64, 256, 0, stream>>>(s1b, W2h, W2l, y2);
    scan2_k<<<NN, 256, 0, stream>>>(y2, out);
}

// Round 17
// 189.657 us; speedup vs baseline: 1.1936x; 1.0077x over previous
//
#include <hip/hip_runtime.h>

// SNN forward (best-known + 8-wave g1s1): [merged preps] ->
// [GEMM1+scan1 fused, 128x128, LDS-dbuf K-loop, 512 thr / 8 waves] ->
// GEMM2 (64-row, 500 blk) -> scan2 (single-phase LDS, static ring).
// f16 split-2: W = hi + lo (both f16), residual ~2^-24 => fp32-grade MFMA.
// Lessons: compile-time ring/dbuf indices (R9); LDS-staged dbuf optimum
// (R10; register-dbuf = VGPR cliff R11/R12); partial-GEMM2 fusion loses (R14);
// 8 waves/block keeps 2 blocks/CU but doubles waves/SIMD to 4 so a draining
// block's barrier stall is covered by the co-resident block (R5 done right).

#define NN 64
#define II 256
#define HH 1024
#define OO 18
#define TT 500

#define D_SR 0.9048374180359595f   // exp(-1/10)
#define C_SR 0.27182818284590454f  // e/10
#define D_RF 0.36787944117144233f  // exp(-1)
#define C_RF 2.718281828459045f    // e
#define THETA 10.0f
#define REFS (-20.0f)

typedef _Float16 f16;
typedef _Float16 f16x8 __attribute__((ext_vector_type(8)));
typedef float f32x4 __attribute__((ext_vector_type(4)));

__device__ __forceinline__ void gl2lds16(const void* g, void* l) {
    __builtin_amdgcn_global_load_lds(
        (const __attribute__((address_space(1))) void*)g,
        (__attribute__((address_space(3))) void*)l, 16, 0, 0);
}

// ---------------- merged prep: X transpose + W1 hi/lo + W2 hi/lo ------------
// grid 3200: [0,2048) prep_x tiles, [2048,3072) W1, [3072,3200) W2.
__launch_bounds__(256)
__global__ void prep_all(const float* __restrict__ X, const float* __restrict__ W1,
                         const float* __restrict__ W2, f16* __restrict__ Xb,
                         f16* __restrict__ W1h, f16* __restrict__ W1l,
                         f16* __restrict__ W2h, f16* __restrict__ W2l) {
    __shared__ float tile[64][65];
    const int b = blockIdx.x;
    const int tid = threadIdx.x;

    if (b < 2048) {
        const int t0 = (b & 7) * 64, i0 = ((b >> 3) & 3) * 64, n = b >> 5;
        const int tx = tid & 63, q = tid >> 6;
        const float* Xn = X + (size_t)n * II * TT;
#pragma unroll 4
        for (int j = 0; j < 16; ++j) {
            int il = j * 4 + q;
            int t = t0 + tx;
            tile[il][tx] = (t < TT) ? Xn[(size_t)(i0 + il) * TT + t] : 0.f;
        }
        __syncthreads();
#pragma unroll 4
        for (int j = 0; j < 16; ++j) {
            int tl = j * 4 + q;
            int t = t0 + tl;
            if (t < TT)
                Xb[((size_t)n * TT + t) * II + i0 + tx] = (f16)tile[tx][tl];
        }
    } else if (b < 3072) {
        int idx = (b - 2048) * 256 + tid;
        float w = W1[idx];
        f16 h = (f16)w;
        f16 l = (f16)(w - (float)h);
        W1h[idx] = h;
        W1l[idx] = l;
    } else {
        int idx = (b - 3072) * 256 + tid;
        int o = idx >> 10;
        float w = (o < OO) ? W2[idx] : 0.f;
        f16 h = (f16)w;
        f16 l = (f16)(w - (float)h);
        W2h[idx] = h;
        W2l[idx] = l;
    }
}

// ---------------- FUSED layer 1: 128x128 tile, dbuf K-loop, 8 waves ---------
// grid (8, 64), 512 thr. Per block: 4 t-chunks of 128.
// Wave layout 2m x 4n: wave w covers rows wm*64+[0,64), cols wn*32+[0,32).
// Staging: wave w stages rows [w*16, w*16+16) of A, Bh, Bl (3 x 1KB each).
__launch_bounds__(512)
__global__ void gemm1_scan1(const f16* __restrict__ Xb, const f16* __restrict__ Wh,
                            const f16* __restrict__ Wl, f16* __restrict__ S1) {
    __shared__ __align__(16) char smem[128 * 132 * 4];  // 67,584 B
    float* yb = (float*)smem;

    const int tid = threadIdx.x;
    const int wave = tid >> 6, lane = tid & 63;

    // XCD swizzle: the 8 h-tiles of one n share an XCD
    const int f = blockIdx.y * 8 + blockIdx.x;
    const int x = f & 7, g = f >> 3;
    const int n = x * 8 + (g & 7);
    const int ht = g >> 3;
    const int h0g = ht * 128;

    const int rbl = wave * 16 + (lane >> 2);   // staged row 0..127
    const int koff = (lane & 3) * 8;
    const f16* gBh0 = Wh + (size_t)(h0g + rbl) * II + koff;
    const f16* gBl0 = Wl + (size_t)(h0g + rbl) * II + koff;

    const int wm = wave & 1, wn = wave >> 1;   // 2m x 4n
    const int fr = lane & 15, kq = lane >> 4;

    float p1 = 0.f, a1 = 0.f, p2 = 0.f, a2 = 0.f;  // scan state (tid<128)

    for (int c = 0; c < 4; ++c) {
        const int t0 = c * 128;
        const int TCe = (TT - t0 < 128) ? (TT - t0) : 128;

        int r0 = rbl; if (r0 > TCe - 1) r0 = TCe - 1;
        const f16* gA0 = Xb + ((size_t)n * TT + t0 + r0) * II + koff;

        auto stage = [&](int kk2, int b) {
            f16* As_b = (f16*)(smem + b * 24576);
            f16* Bh_b = As_b + 4096;   // f16 elements: As = 128*32 = 4096
            f16* Bl_b = As_b + 8192;
            const int ko = kk2 * 32;
            gl2lds16(gA0 + ko, As_b + wave * 512);
            gl2lds16(gBh0 + ko, Bh_b + wave * 512);
            gl2lds16(gBl0 + ko, Bl_b + wave * 512);
        };

        stage(0, 0);  // previous chunk's post-scan barrier protects yb base

        f32x4 acc[4][2] = {};
        for (int kk = 0; kk < 8; ++kk) {
            __syncthreads();                 // buf[kk&1] DMA drained here
            if (kk < 7) stage(kk + 1, (kk + 1) & 1);

            const f16* As_b = (const f16*)(smem + (kk & 1) * 24576);
            const f16* Bh_b = As_b + 4096;
            const f16* Bl_b = As_b + 8192;

            f16x8 av[4], bhv[2], blv[2];
#pragma unroll
            for (int i = 0; i < 4; ++i)
                av[i] = *(const f16x8*)(As_b + (wm * 64 + i * 16 + fr) * 32 + kq * 8);
#pragma unroll
            for (int j = 0; j < 2; ++j) {
                bhv[j] = *(const f16x8*)(Bh_b + (wn * 32 + j * 16 + fr) * 32 + kq * 8);
                blv[j] = *(const f16x8*)(Bl_b + (wn * 32 + j * 16 + fr) * 32 + kq * 8);
            }
#pragma unroll
            for (int i = 0; i < 4; ++i)
#pragma unroll
                for (int j = 0; j < 2; ++j) {
                    acc[i][j] = __builtin_amdgcn_mfma_f32_16x16x32_f16(av[i], bhv[j], acc[i][j], 0, 0, 0);
                    acc[i][j] = __builtin_amdgcn_mfma_f32_16x16x32_f16(av[i], blv[j], acc[i][j], 0, 0, 0);
                }
        }
        __syncthreads();  // all frag reads done before epilogue overwrites staging

        // epilogue: acc -> yb (t-major, stride 132)
#pragma unroll
        for (int i = 0; i < 4; ++i)
#pragma unroll
            for (int j = 0; j < 2; ++j) {
                int tr = wm * 64 + i * 16 + kq * 4;
                int hc = wn * 32 + j * 16 + fr;
#pragma unroll
                for (int r = 0; r < 4; ++r)
                    yb[(tr + r) * 132 + hc] = acc[i][j][r];
            }
        __syncthreads();

        // sequential scan (waves 0-1); 8-deep ring; spikes -> global directly
        if (tid < 128) {
            f16* sq = S1 + ((size_t)n * TT + t0) * HH + h0g + tid;
            float rb_[8];
#pragma unroll
            for (int j = 0; j < 8; ++j) rb_[j] = yb[j * 132 + tid];
            int t = 0;
            for (; t + 8 <= TCe; t += 8) {
#pragma unroll
                for (int j = 0; j < 8; ++j) {
                    float xv = rb_[j];
                    int tn = t + j + 8;
                    rb_[j] = (tn < TCe) ? yb[tn * 132 + tid] : 0.f;
                    a1 = D_SR * (a1 + p1);
                    p1 = D_SR * p1 + xv;
                    float ut = C_SR * a1;
                    a2 = D_RF * (a2 + p2);
                    float u = ut + C_RF * a2;
                    float s = (u >= THETA) ? 1.0f : 0.0f;
                    p2 = D_RF * p2 + REFS * s;
                    sq[(size_t)(t + j) * HH] = (f16)s;
                }
            }
            int rem = TCe - t;
#pragma unroll
            for (int j = 0; j < 8; ++j) {
                if (j < rem) {
                    float xv = rb_[j];
                    a1 = D_SR * (a1 + p1);
                    p1 = D_SR * p1 + xv;
                    float ut = C_SR * a1;
                    a2 = D_RF * (a2 + p2);
                    float u = ut + C_RF * a2;
                    float s = (u >= THETA) ? 1.0f : 0.0f;
                    p2 = D_RF * p2 + REFS * s;
                    sq[(size_t)(t + j) * HH] = (f16)s;
                }
            }
        }
        __syncthreads();  // yb reads done; next chunk's staging may overwrite
    }
}

// ---------------- GEMM2 (MFMA, split-f16, dbuf, 64-row tiles) ---------------
// grid 500 (2 blocks/CU); 256 thr; tile 64 m x 32 o; K=1024, BK=32.
__launch_bounds__(256)
__global__ void gemm2_mfma(const f16* __restrict__ S1, const f16* __restrict__ W2h,
                           const f16* __restrict__ W2l, float* __restrict__ Y2) {
    __shared__ __align__(16) f16 As[2][64 * 32];  // 2 x 4 KB
    __shared__ __align__(16) f16 Bh[2][32 * 32];  // 2 x 2 KB
    __shared__ __align__(16) f16 Bl[2][32 * 32];  // 2 x 2 KB

    const int tid = threadIdx.x;
    const int wave = tid >> 6, lane = tid & 63;
    const int m0 = blockIdx.x * 64;
    const int fr = lane & 15, kq = lane >> 4;

    const f16* gA = S1 + (size_t)(m0 + wave * 16 + (lane >> 2)) * HH + (lane & 3) * 8;
    const f16* gB = (wave < 2 ? W2h : W2l) + (size_t)((wave & 1) * 16 + (lane >> 2)) * HH + (lane & 3) * 8;

    auto stage = [&](int kk2, int b) {
        const int ko = kk2 * 32;
        gl2lds16(gA + ko, &As[b][wave * 512]);
        gl2lds16(gB + ko, (wave < 2 ? &Bh[b][0] : &Bl[b][0]) + (wave & 1) * 512);
    };

    stage(0, 0);

    f32x4 acc[2] = {};
    for (int kk = 0; kk < HH / 32; ++kk) {
        __syncthreads();
        if (kk < HH / 32 - 1) stage(kk + 1, (kk + 1) & 1);
        const int b = kk & 1;

        f16x8 a, bh[2], bl[2];
        a = *(const f16x8*)(&As[b][(wave * 16 + fr) * 32 + kq * 8]);
#pragma unroll
        for (int j = 0; j < 2; ++j) {
            bh[j] = *(const f16x8*)(&Bh[b][(j * 16 + fr) * 32 + kq * 8]);
            bl[j] = *(const f16x8*)(&Bl[b][(j * 16 + fr) * 32 + kq * 8]);
        }
#pragma unroll
        for (int j = 0; j < 2; ++j) {
            acc[j] = __builtin_amdgcn_mfma_f32_16x16x32_f16(a, bh[j], acc[j], 0, 0, 0);
            acc[j] = __builtin_amdgcn_mfma_f32_16x16x32_f16(a, bl[j], acc[j], 0, 0, 0);
        }
    }

#pragma unroll
    for (int j = 0; j < 2; ++j) {
        int rbase = m0 + wave * 16 + kq * 4;
        int cc = j * 16 + fr;
        float* p = Y2 + (size_t)rbase * 32 + cc;
#pragma unroll
        for (int r = 0; r < 4; ++r)
            p[(size_t)r * 32] = acc[j][r];
    }
}

// ---------------- scan2: single-phase LDS, static-index ring ----------------
__launch_bounds__(256)
__global__ void scan2_k(const float* __restrict__ Y2, float* __restrict__ Out) {
    __shared__ float yc[TT * 32];    // 64,000 B
    __shared__ float sb[OO * TT];    // 36,000 B
    const int n = blockIdx.x, tid = threadIdx.x;

    const float4* src = (const float4*)(Y2 + (size_t)n * TT * 32);
    float4* dst = (float4*)yc;
    for (int i = tid; i < TT * 8; i += 256) dst[i] = src[i];
    __syncthreads();

    if (tid < 32) {
        float p1 = 0.f, a1 = 0.f, p2 = 0.f, a2 = 0.f;
        float rb_[8];
#pragma unroll
        for (int j = 0; j < 8; ++j) rb_[j] = yc[j * 32 + tid];
        int t = 0;
        for (; t + 8 <= TT; t += 8) {
#pragma unroll
            for (int j = 0; j < 8; ++j) {
                float xv = rb_[j];
                int tn = t + j + 8;
                rb_[j] = (tn < TT) ? yc[tn * 32 + tid] : 0.f;
                a1 = D_SR * (a1 + p1);
                p1 = D_SR * p1 + xv;
                float ut = C_SR * a1;
                a2 = D_RF * (a2 + p2);
                float u = ut + C_RF * a2;
                float s = (u >= THETA) ? 1.0f : 0.0f;
                p2 = D_RF * p2 + REFS * s;
                if (tid < OO) sb[tid * TT + t + j] = s;
            }
        }
#pragma unroll
        for (int j = 0; j < 8; ++j) {
            if (t + j < TT) {
                float xv = rb_[j];
                a1 = D_SR * (a1 + p1);
                p1 = D_SR * p1 + xv;
                float ut = C_SR * a1;
                a2 = D_RF * (a2 + p2);
                float u = ut + C_RF * a2;
                float s = (u >= THETA) ? 1.0f : 0.0f;
                p2 = D_RF * p2 + REFS * s;
                if (tid < OO) sb[tid * TT + t + j] = s;
            }
        }
    }
    __syncthreads();

    float* on = Out + (size_t)n * OO * TT;
    for (int e = tid; e < OO * TT; e += 256) on[e] = sb[e];
}

extern "C" void kernel_launch(void* const* d_in, const int* in_sizes, int n_in,
                              void* d_out, int out_size, void* d_ws, size_t ws_size,
                              hipStream_t stream) {
    const float* X  = (const float*)d_in[0];
    const float* W1 = (const float*)d_in[1];
    const float* W2 = (const float*)d_in[2];
    float* out = (float*)d_out;

    const size_t s_s1 = (size_t)NN * TT * HH * 2;   // 65,536,000
    const size_t s_Xb = (size_t)NN * TT * II * 2;   // 16,384,000
    const size_t s_W  = (size_t)HH * II * 2;        //    524,288 (x2)
    const size_t s_W2 = (size_t)32 * HH * 2;        //     65,536 (x2)
    // + y2 4,096,000 => ~87 MB total

    char* w = (char*)d_ws;
    f16*   s1b = (f16*)w;  w += s_s1;
    f16*   Xb  = (f16*)w;  w += s_Xb;
    f16*   W1h = (f16*)w;  w += s_W;
    f16*   W1l = (f16*)w;  w += s_W;
    f16*   W2h = (f16*)w;  w += s_W2;
    f16*   W2l = (f16*)w;  w += s_W2;
    float* y2  = (float*)w;

    prep_all<<<3200, 256, 0, stream>>>(X, W1, W2, Xb, W1h, W1l, W2h, W2l);

    gemm1_scan1<<<dim3(8, NN), 512, 0, stream>>>(Xb, W1h, W1l, s1b);

    gemm2_mfma<<<(NN * TT) / 64, 256, 0, stream>>>(s1b, W2h, W2l, y2);
    scan2_k<<<NN, 256, 0, stream>>>(y2, out);
}